// Round 1
// baseline (1022.492 us; speedup 1.0000x reference)
//
#include <hip/hip_runtime.h>
#include <hip/hip_bf16.h>
#include <math.h>

// Problem constants
#define PB 4
#define PN 8192
#define PD 1024
#define PH 16
#define PDH 64
#define PGH 256

typedef __bf16 bf16x8 __attribute__((ext_vector_type(8)));
typedef __bf16 bf16x2 __attribute__((ext_vector_type(2)));
typedef float f32x4 __attribute__((ext_vector_type(4)));

__device__ inline float gelu_exact(float x) {
    return 0.5f * x * (1.0f + erff(x * 0.70710678118654752440f));
}

// ---------------------------------------------------------------- convert x -> bf16
__global__ void convert_x(const float* __restrict__ x, __bf16* __restrict__ xb) {
    int i = (blockIdx.x * 256 + threadIdx.x) * 8;
    float4 f0 = *(const float4*)(x + i);
    float4 f1 = *(const float4*)(x + i + 4);
    bf16x8 o;
    o[0] = (__bf16)f0.x; o[1] = (__bf16)f0.y; o[2] = (__bf16)f0.z; o[3] = (__bf16)f0.w;
    o[4] = (__bf16)f1.x; o[5] = (__bf16)f1.y; o[6] = (__bf16)f1.z; o[7] = (__bf16)f1.w;
    *(bf16x8*)(xb + i) = o;
}

// ------------------------------------------- transpose+convert w_v, w_o -> bf16 N x K
__global__ void transpose_w(const float* __restrict__ wv, const float* __restrict__ wo,
                            __bf16* __restrict__ wvt, __bf16* __restrict__ wot) {
    int idx = blockIdx.x * 256 + threadIdx.x;      // 0 .. 1048575
    const float* src = blockIdx.y ? wo : wv;
    __bf16* dst = blockIdx.y ? wot : wvt;
    int r = idx >> 10, c = idx & 1023;
    dst[c * PD + r] = (__bf16)src[idx];
}

// ---------------------------------------------------------------- xsum[b,d] = sum_n x
__global__ void reduce_x(const float* __restrict__ x, float* __restrict__ xsum) {
    int b = blockIdx.z;
    int d = blockIdx.y * 256 + threadIdx.x;
    int n0 = blockIdx.x * 512;
    const float* p = x + ((size_t)b * PN + n0) * PD + d;
    float s = 0.0f;
    for (int i = 0; i < 512; i++) s += p[(size_t)i * PD];
    atomicAdd(&xsum[b * PD + d], s);
}

// --------------------------------- bar_q = (xsum/N) @ w_q, then LayerNorm over DH=64
__global__ void barq_ln(const float* __restrict__ xsum, const float* __restrict__ w_q,
                        const float* __restrict__ ln_g, const float* __restrict__ ln_b,
                        float* __restrict__ bar_ln) {
    int b = blockIdx.y;
    int c = blockIdx.x * 256 + threadIdx.x;
    const float* xs = xsum + b * PD;
    float acc = 0.0f;
    for (int k = 0; k < PD; k++) acc += xs[k] * w_q[k * PD + c];
    float bar = acc * (1.0f / (float)PN);
    // LN over the 64-lane wave (one head per wave: c groups of 64 align with waves)
    float mu = bar;
    for (int o = 32; o > 0; o >>= 1) mu += __shfl_xor(mu, o, 64);
    mu *= (1.0f / 64.0f);
    float d0 = bar - mu;
    float vv = d0 * d0;
    for (int o = 32; o > 0; o >>= 1) vv += __shfl_xor(vv, o, 64);
    vv *= (1.0f / 64.0f);
    int dh = c & 63;
    bar_ln[b * PD + c] = d0 * rsqrtf(vv + 1e-5f) * ln_g[dh] + ln_b[dh];
}

// ---------------------------- t_gate = gelu(bar@gate_w1); t_wrm = gelu(bar@wrm_w1)
__global__ void small1(const float* __restrict__ bar_ln, const float* __restrict__ gw1,
                       const float* __restrict__ ww1, float* __restrict__ tg,
                       float* __restrict__ tw) {
    int bh = blockIdx.x;
    int j = threadIdx.x;
    __shared__ float bl[PDH];
    if (j < PDH) bl[j] = bar_ln[bh * PDH + j];
    __syncthreads();
    float a1 = 0.0f, a2 = 0.0f;
    for (int k = 0; k < PDH; k++) {
        float bv = bl[k];
        a1 += bv * gw1[k * PGH + j];
        a2 += bv * ww1[k * PGH + j];
    }
    tg[bh * PGH + j] = gelu_exact(a1);
    tw[bh * PGH + j] = gelu_exact(a2);
}

// ---------------------- g_raw = t_gate@gate_w2 (64x16384); s = t_wrm@wrm_w2 (64x8192)
__global__ void small2(const float* __restrict__ tg, const float* __restrict__ tw,
                       const float* __restrict__ gw2, const float* __restrict__ ww2,
                       float* __restrict__ g_raw, float* __restrict__ s_full) {
    int chunk = blockIdx.x;            // 0..95 (0..63 gate, 64..95 wrm)
    int bh0 = blockIdx.y * 8;          // 8 bh rows per block
    bool isg = chunk < 64;
    const float* t = isg ? tg : tw;
    const float* w2 = isg ? gw2 : ww2;
    int stride = isg ? (2 * PN) : PN;
    int col = (isg ? chunk : chunk - 64) * 256 + threadIdx.x;
    __shared__ float tl[8][PGH];
    #pragma unroll
    for (int i = 0; i < 8; i++) tl[i][threadIdx.x] = t[(bh0 + i) * PGH + threadIdx.x];
    __syncthreads();
    float acc[8] = {0, 0, 0, 0, 0, 0, 0, 0};
    for (int k = 0; k < PGH; k++) {
        float w = w2[(size_t)k * stride + col];
        #pragma unroll
        for (int i = 0; i < 8; i++) acc[i] += tl[i][k] * w;
    }
    #pragma unroll
    for (int i = 0; i < 8; i++) {
        if (isg) g_raw[(size_t)(bh0 + i) * (2 * PN) + col] = acc[i];
        else     s_full[(size_t)(bh0 + i) * PN + col] = acc[i];
    }
}

// ---------------------------------------------------------------- MFMA GEMM (B^T form)
// C[M x 1024] = A[M x 1024] * Bt[1024 x 1024]^T ; 128x128 tile, 4 waves, 64x64/wave
template<int OUT_BF16>
__global__ __launch_bounds__(256) void gemm_bt(const __bf16* __restrict__ A,
                                               const __bf16* __restrict__ Bt,
                                               __bf16* __restrict__ Cb,
                                               float* __restrict__ Cf) {
    constexpr int K = PD, Nc = PD, LDK = 40;   // +8 bf16 pad keeps 16B align, spreads banks
    __shared__ __attribute__((aligned(16))) __bf16 As[128 * LDK];
    __shared__ __attribute__((aligned(16))) __bf16 Bs[128 * LDK];
    const int tid = threadIdx.x;
    const int lane = tid & 63;
    const int wave = tid >> 6;
    const int wm = (wave >> 1) << 6;
    const int wn = (wave & 1) << 6;
    const int tileM = blockIdx.y << 7;
    const int tileN = blockIdx.x << 7;
    const int r = tid >> 2;        // staging row (0..63; +64 in second chunk)
    const int cg = tid & 3;        // 8-elem k group
    const int mrow = lane & 15;
    const int k0 = (lane >> 4) << 3;

    f32x4 acc[4][4] = {};
    const __bf16* Aptr = A + (size_t)(tileM + r) * K + cg * 8;
    const __bf16* Bptr = Bt + (size_t)(tileN + r) * K + cg * 8;

    for (int kt = 0; kt < K; kt += 32) {
        __syncthreads();
        *(uint4*)&As[r * LDK + cg * 8]        = *(const uint4*)(Aptr + kt);
        *(uint4*)&As[(r + 64) * LDK + cg * 8] = *(const uint4*)(Aptr + (size_t)64 * K + kt);
        *(uint4*)&Bs[r * LDK + cg * 8]        = *(const uint4*)(Bptr + kt);
        *(uint4*)&Bs[(r + 64) * LDK + cg * 8] = *(const uint4*)(Bptr + (size_t)64 * K + kt);
        __syncthreads();
        bf16x8 af[4], bfr[4];
        #pragma unroll
        for (int i = 0; i < 4; i++) af[i]  = *(const bf16x8*)&As[(wm + i * 16 + mrow) * LDK + k0];
        #pragma unroll
        for (int j = 0; j < 4; j++) bfr[j] = *(const bf16x8*)&Bs[(wn + j * 16 + mrow) * LDK + k0];
        #pragma unroll
        for (int i = 0; i < 4; i++)
            #pragma unroll
            for (int j = 0; j < 4; j++)
                acc[i][j] = __builtin_amdgcn_mfma_f32_16x16x32_bf16(af[i], bfr[j], acc[i][j], 0, 0, 0);
    }

    const int rq = (lane >> 4) << 2;
    #pragma unroll
    for (int i = 0; i < 4; i++) {
        #pragma unroll
        for (int rr = 0; rr < 4; rr++) {
            int row = tileM + wm + i * 16 + rq + rr;
            size_t base = (size_t)row * Nc + tileN + wn + mrow;
            #pragma unroll
            for (int j = 0; j < 4; j++) {
                float val = acc[i][j][rr];
                if (OUT_BF16) Cb[base + j * 16] = (__bf16)val;
                else          Cf[base + j * 16] = val;
            }
        }
    }
}

// ------------------------------------------------- FFT conv + hadamard/scale epilogue
// One block per (b, h, dh-pair). Packed 2-real-in-1-complex fwd FFT, spectral gate,
// symmetrized packed inverse FFT, then the even/odd * s * butterfly epilogue.
__global__ __launch_bounds__(256) void fftconv(const __bf16* __restrict__ v,
                                               const float* __restrict__ g_raw,
                                               const float* __restrict__ s_full,
                                               __bf16* __restrict__ y) {
    __shared__ float2 Z[PN];   // 64 KB
    const int tid = threadIdx.x;
    const int blk = blockIdx.x;          // 2048 = 64 bh * 32 pairs
    const int bh = blk >> 5;
    const int pr = blk & 31;
    const int b = bh >> 4;
    const int h = bh & 15;
    const int dh = pr << 1;
    const __bf16* vp = v + ((size_t)b * PN * PD + h * PDH + dh);

    // load (bit-reversed positions for DIT)
    for (int n = tid; n < PN; n += 256) {
        bf16x2 pv = *(const bf16x2*)(vp + (size_t)n * PD);
        int p = __brev((unsigned)n) >> 19;
        Z[p] = make_float2((float)pv.x, (float)pv.y);
    }
    __syncthreads();

    // forward DIT radix-2, 13 stages, natural-order output
    for (int s = 0; s < 13; s++) {
        int half = 1 << s;
        float angf = -6.283185307179586f / (float)(2 << s);
        for (int q = tid; q < PN / 2; q += 256) {
            int j = q & (half - 1);
            int i = ((q >> s) << (s + 1)) + j;
            float sn, cs;
            __sincosf(angf * (float)j, &sn, &cs);
            float2 u = Z[i], t = Z[i + half];
            float tr = t.x * cs - t.y * sn;
            float ti = t.x * sn + t.y * cs;
            Z[i]        = make_float2(u.x + tr, u.y + ti);
            Z[i + half] = make_float2(u.x - tr, u.y - ti);
        }
        __syncthreads();
    }

    // spectral stage: unpack the two real spectra, gate by g, re-pack the
    // conj-symmetrized parts so one inverse FFT yields both real signals.
    const float* gr = g_raw + (size_t)bh * (2 * PN);
    const float* gi = gr + PN;
    for (int k = tid; k <= PN / 2; k += 256) {
        int Nk = (PN - k) & (PN - 1);
        float2 Za = Z[k], Zb = Z[Nk];
        float v1r = 0.5f * (Za.x + Zb.x), v1i = 0.5f * (Za.y - Zb.y);
        float v2r = 0.5f * (Za.y + Zb.y), v2i = 0.5f * (Zb.x - Za.x);
        float grk = gr[k], gik = gi[k];
        float grn = gr[Nk], gin = gi[Nk];
        float y1r = v1r * grk - v1i * gik, y1i = v1r * gik + v1i * grk;
        float y2r = v2r * grk - v2i * gik, y2i = v2r * gik + v2i * grk;
        // Y at Nk uses conj(V1k), conj(V2k):
        float y1nr = v1r * grn + v1i * gin, y1ni = v1r * gin - v1i * grn;
        float y2nr = v2r * grn + v2i * gin, y2ni = v2r * gin - v2i * grn;
        float ys1r = 0.5f * (y1r + y1nr), ys1i = 0.5f * (y1i - y1ni);
        float ys2r = 0.5f * (y2r + y2nr), ys2i = 0.5f * (y2i - y2ni);
        Z[k] = make_float2(ys1r - ys2i, ys1i + ys2r);
        if (Nk != k) Z[Nk] = make_float2(ys1r + ys2i, ys2r - ys1i);
    }
    __syncthreads();

    // inverse DIF radix-2 (+i twiddles), natural input -> bit-reversed output
    for (int s = 12; s >= 0; s--) {
        int half = 1 << s;
        float angf = 6.283185307179586f / (float)(2 << s);
        for (int q = tid; q < PN / 2; q += 256) {
            int j = q & (half - 1);
            int i = ((q >> s) << (s + 1)) + j;
            float sn, cs;
            __sincosf(angf * (float)j, &sn, &cs);
            float2 u = Z[i], t = Z[i + half];
            Z[i] = make_float2(u.x + t.x, u.y + t.y);
            float dx = u.x - t.x, dy = u.y - t.y;
            Z[i + half] = make_float2(dx * cs - dy * sn, dx * sn + dy * cs);
        }
        __syncthreads();
    }

    // epilogue: v_tilde + second-butterfly(s * first-butterfly(v_tilde))
    const float* sp = s_full + (size_t)bh * PN;
    __bf16* yp = y + ((size_t)b * PN * PD + h * PDH + dh);
    const float inv = 1.0f / (float)PN;
    const float I2 = 0.70710678118654752440f;
    for (int np = tid; np < PN / 2; np += 256) {
        int n0 = np << 1, n1 = n0 | 1;
        float2 z0 = Z[__brev((unsigned)n0) >> 19];
        float2 z1 = Z[__brev((unsigned)n1) >> 19];
        float s0 = sp[np], s1v = sp[np + PN / 2];
        float ax = z0.x * inv, bx = z1.x * inv;
        float ay = z0.y * inv, by = z1.y * inv;
        float wlx = (ax + bx) * I2 * s0, whx = (ax - bx) * I2 * s1v;
        float evx = (wlx + whx) * I2,   odx = (wlx - whx) * I2;
        float wly = (ay + by) * I2 * s0, why = (ay - by) * I2 * s1v;
        float evy = (wly + why) * I2,   ody = (wly - why) * I2;
        bf16x2 o0, o1;
        o0.x = (__bf16)(ax + evx); o0.y = (__bf16)(ay + evy);
        o1.x = (__bf16)(bx + odx); o1.y = (__bf16)(by + ody);
        *(bf16x2*)(yp + (size_t)n0 * PD) = o0;
        *(bf16x2*)(yp + (size_t)n1 * PD) = o1;
    }
}

// ================================================================ launcher
extern "C" void kernel_launch(void* const* d_in, const int* in_sizes, int n_in,
                              void* d_out, int out_size, void* d_ws, size_t ws_size,
                              hipStream_t stream) {
    const float* x    = (const float*)d_in[0];
    const float* w_q  = (const float*)d_in[1];
    const float* w_v  = (const float*)d_in[2];
    const float* w_o  = (const float*)d_in[3];
    const float* ln_g = (const float*)d_in[4];
    const float* ln_b = (const float*)d_in[5];
    const float* gw1  = (const float*)d_in[6];
    const float* gw2  = (const float*)d_in[7];
    const float* ww1  = (const float*)d_in[8];
    const float* ww2  = (const float*)d_in[9];
    float* out = (float*)d_out;

    const size_t XE = (size_t)PB * PN * PD;        // 33554432
    __bf16* xb   = (__bf16*)d_ws;                  // also reused as y after GEMM1
    __bf16* vb   = xb + XE;
    __bf16* wvt  = vb + XE;
    __bf16* wot  = wvt + (size_t)PD * PD;
    float*  xsum = (float*)(wot + (size_t)PD * PD);
    float*  bar  = xsum + PB * PD;
    float*  tg   = bar + PB * PD;
    float*  tw   = tg + 64 * PGH;
    float*  graw = tw + 64 * PGH;
    float*  sful = graw + (size_t)64 * 2 * PN;

    hipMemsetAsync(xsum, 0, PB * PD * sizeof(float), stream);

    convert_x<<<XE / (256 * 8), 256, 0, stream>>>(x, xb);
    transpose_w<<<dim3(PD * PD / 256, 2), 256, 0, stream>>>(w_v, w_o, wvt, wot);
    reduce_x<<<dim3(PN / 512, PD / 256, PB), 256, 0, stream>>>(x, xsum);
    barq_ln<<<dim3(PD / 256, PB), 256, 0, stream>>>(xsum, w_q, ln_g, ln_b, bar);
    small1<<<PB * PH, 256, 0, stream>>>(bar, gw1, ww1, tg, tw);
    small2<<<dim3(96, 8), 256, 0, stream>>>(tg, tw, gw2, ww2, graw, sful);
    gemm_bt<1><<<dim3(PD / 128, PB * PN / 128), 256, 0, stream>>>(xb, wvt, vb, nullptr);
    fftconv<<<PB * PH * (PDH / 2), 256, 0, stream>>>(vb, graw, sful, xb);
    gemm_bt<0><<<dim3(PD / 128, PB * PN / 128), 256, 0, stream>>>(xb, wot, nullptr, out);
}

// Round 2
// 848.489 us; speedup vs baseline: 1.2051x; 1.2051x over previous
//
#include <hip/hip_runtime.h>
#include <hip/hip_bf16.h>
#include <math.h>

#define PB 4
#define PN 8192
#define PD 1024
#define PH 16
#define PDH 64
#define PGH 256

typedef __bf16 bf16x8 __attribute__((ext_vector_type(8)));
typedef __bf16 bf16x2 __attribute__((ext_vector_type(2)));
typedef float f32x4 __attribute__((ext_vector_type(4)));
typedef unsigned int u32;

typedef __attribute__((address_space(3))) void lds_void_t;
typedef const __attribute__((address_space(1))) void gbl_void_t;
#define ASYNC_COPY16(gp, lp) \
    __builtin_amdgcn_global_load_lds((gbl_void_t*)(gp), (lds_void_t*)(lp), 16, 0, 0)

__device__ inline float gelu_exact(float x) {
    return 0.5f * x * (1.0f + erff(x * 0.70710678118654752440f));
}

__device__ inline float2 f2(float x, float y) { return make_float2(x, y); }
__device__ inline float2 cadd(float2 a, float2 b) { return f2(a.x + b.x, a.y + b.y); }
__device__ inline float2 csub(float2 a, float2 b) { return f2(a.x - b.x, a.y - b.y); }
__device__ inline float2 cmul(float2 a, float2 b) {
    return f2(a.x * b.x - a.y * b.y, a.x * b.y + a.y * b.x);
}

// XOR swizzle: uniform ~4-way (b64 floor) for every access pattern in the FFT
#define PHYS(i) ((i) ^ (((i) >> 4) & 15))

// ---------------------------------------------------------------- convert x -> bf16
__global__ void convert_x(const float* __restrict__ x, __bf16* __restrict__ xb) {
    int i = (blockIdx.x * 256 + threadIdx.x) * 8;
    float4 f0 = *(const float4*)(x + i);
    float4 f1 = *(const float4*)(x + i + 4);
    bf16x8 o;
    o[0] = (__bf16)f0.x; o[1] = (__bf16)f0.y; o[2] = (__bf16)f0.z; o[3] = (__bf16)f0.w;
    o[4] = (__bf16)f1.x; o[5] = (__bf16)f1.y; o[6] = (__bf16)f1.z; o[7] = (__bf16)f1.w;
    *(bf16x8*)(xb + i) = o;
}

// ------------------------------------------- transpose+convert w_v, w_o -> bf16 N x K
__global__ void transpose_w(const float* __restrict__ wv, const float* __restrict__ wo,
                            __bf16* __restrict__ wvt, __bf16* __restrict__ wot) {
    int idx = blockIdx.x * 256 + threadIdx.x;
    const float* src = blockIdx.y ? wo : wv;
    __bf16* dst = blockIdx.y ? wot : wvt;
    int r = idx >> 10, c = idx & 1023;
    dst[c * PD + r] = (__bf16)src[idx];
}

// ---------------------------------------------------------------- xsum[b,d] = sum_n x
__global__ void reduce_x(const float* __restrict__ x, float* __restrict__ xsum) {
    int b = blockIdx.z;
    int d = blockIdx.y * 256 + threadIdx.x;
    int n0 = blockIdx.x * 512;
    const float* p = x + ((size_t)b * PN + n0) * PD + d;
    float s = 0.0f;
    for (int i = 0; i < 512; i++) s += p[(size_t)i * PD];
    atomicAdd(&xsum[b * PD + d], s);
}

// --------------------------------- bar_q = (xsum/N) @ w_q, then LayerNorm over DH=64
__global__ void barq_ln(const float* __restrict__ xsum, const float* __restrict__ w_q,
                        const float* __restrict__ ln_g, const float* __restrict__ ln_b,
                        float* __restrict__ bar_ln) {
    int b = blockIdx.y;
    int c = blockIdx.x * 256 + threadIdx.x;
    const float* xs = xsum + b * PD;
    float acc = 0.0f;
    for (int k = 0; k < PD; k++) acc += xs[k] * w_q[k * PD + c];
    float bar = acc * (1.0f / (float)PN);
    float mu = bar;
    for (int o = 32; o > 0; o >>= 1) mu += __shfl_xor(mu, o, 64);
    mu *= (1.0f / 64.0f);
    float d0 = bar - mu;
    float vv = d0 * d0;
    for (int o = 32; o > 0; o >>= 1) vv += __shfl_xor(vv, o, 64);
    vv *= (1.0f / 64.0f);
    int dh = c & 63;
    bar_ln[b * PD + c] = d0 * rsqrtf(vv + 1e-5f) * ln_g[dh] + ln_b[dh];
}

// ---------------------------- t_gate = gelu(bar@gate_w1); t_wrm = gelu(bar@wrm_w1)
__global__ void small1(const float* __restrict__ bar_ln, const float* __restrict__ gw1,
                       const float* __restrict__ ww1, float* __restrict__ tg,
                       float* __restrict__ tw) {
    int bh = blockIdx.x;
    int j = threadIdx.x;
    __shared__ float bl[PDH];
    if (j < PDH) bl[j] = bar_ln[bh * PDH + j];
    __syncthreads();
    float a1 = 0.0f, a2 = 0.0f;
    for (int k = 0; k < PDH; k++) {
        float bv = bl[k];
        a1 += bv * gw1[k * PGH + j];
        a2 += bv * ww1[k * PGH + j];
    }
    tg[bh * PGH + j] = gelu_exact(a1);
    tw[bh * PGH + j] = gelu_exact(a2);
}

// ---------------------- g_raw = t_gate@gate_w2 (64x16384); s = t_wrm@wrm_w2 (64x8192)
__global__ void small2(const float* __restrict__ tg, const float* __restrict__ tw,
                       const float* __restrict__ gw2, const float* __restrict__ ww2,
                       float* __restrict__ g_raw, float* __restrict__ s_full) {
    int chunk = blockIdx.x;
    int bh0 = blockIdx.y * 8;
    bool isg = chunk < 64;
    const float* t = isg ? tg : tw;
    const float* w2 = isg ? gw2 : ww2;
    int stride = isg ? (2 * PN) : PN;
    int col = (isg ? chunk : chunk - 64) * 256 + threadIdx.x;
    __shared__ float tl[8][PGH];
    #pragma unroll
    for (int i = 0; i < 8; i++) tl[i][threadIdx.x] = t[(bh0 + i) * PGH + threadIdx.x];
    __syncthreads();
    float acc[8] = {0, 0, 0, 0, 0, 0, 0, 0};
    for (int k = 0; k < PGH; k++) {
        float w = w2[(size_t)k * stride + col];
        #pragma unroll
        for (int i = 0; i < 8; i++) acc[i] += tl[i][k] * w;
    }
    #pragma unroll
    for (int i = 0; i < 8; i++) {
        if (isg) g_raw[(size_t)(bh0 + i) * (2 * PN) + col] = acc[i];
        else     s_full[(size_t)(bh0 + i) * PN + col] = acc[i];
    }
}

// ------------------------------------- 4B-element transpose: (B,R,C) -> (B,C,R) uint
__global__ __launch_bounds__(256) void transpose32(const u32* __restrict__ src,
                                                   u32* __restrict__ dst, int R, int C) {
    __shared__ u32 T[64 * 65];
    int r0 = blockIdx.y * 64, c0 = blockIdx.x * 64;
    int t = threadIdx.x;
    int rr = t >> 4, c4 = (t & 15) * 4;
    const u32* sp = src + ((size_t)blockIdx.z * R + r0) * C + c0;
    #pragma unroll
    for (int it = 0; it < 4; it++) {
        int row = rr + it * 16;
        uint4 vv = *(const uint4*)(sp + (size_t)row * C + c4);
        T[(c4 + 0) * 65 + row] = vv.x;
        T[(c4 + 1) * 65 + row] = vv.y;
        T[(c4 + 2) * 65 + row] = vv.z;
        T[(c4 + 3) * 65 + row] = vv.w;
    }
    __syncthreads();
    u32* dp = dst + ((size_t)blockIdx.z * C + c0) * R + r0;
    #pragma unroll
    for (int it = 0; it < 4; it++) {
        int row = rr + it * 16;
        uint4 o;
        o.x = T[row * 65 + c4 + 0];
        o.y = T[row * 65 + c4 + 1];
        o.z = T[row * 65 + c4 + 2];
        o.w = T[row * 65 + c4 + 3];
        *(uint4*)(dp + (size_t)row * R + c4) = o;
    }
}

// ---------------------------------------------------------------- MFMA GEMM (B^T form)
// C[M x 1024] = A[M x 1024] * Bt[1024 x 1024]^T ; 128x128 tile, m97-style
// global_load_lds width=16 staging (LDS dest == wave base + lane*16 == tid*16).
template<int OUT_BF16>
__global__ __launch_bounds__(256) void gemm_bt(const __bf16* __restrict__ A,
                                               const __bf16* __restrict__ Bt,
                                               __bf16* __restrict__ Cb,
                                               float* __restrict__ Cf) {
    constexpr int K = PD, Nc = PD, LDK = 32;
    __shared__ __attribute__((aligned(16))) __bf16 As[128 * LDK];
    __shared__ __attribute__((aligned(16))) __bf16 Bs[128 * LDK];
    const int tid = threadIdx.x;
    const int lane = tid & 63;
    const int wave = tid >> 6;
    const int wm = (wave >> 1) << 6;
    const int wn = (wave & 1) << 6;
    const int tileM = blockIdx.y << 7;
    const int tileN = blockIdx.x << 7;
    const int r = tid >> 2;        // staging row (0..63; +64 in second chunk)
    const int cg = tid & 3;        // 8-elem k group
    const int mrow = lane & 15;
    const int k0 = (lane >> 4) << 3;

    f32x4 acc[4][4] = {};
    const __bf16* Aptr = A + (size_t)(tileM + r) * K + cg * 8;
    const __bf16* Bptr = Bt + (size_t)(tileN + r) * K + cg * 8;

    for (int kt = 0; kt < K; kt += 32) {
        __syncthreads();
        ASYNC_COPY16(Aptr + kt,                  As + tid * 8);
        ASYNC_COPY16(Aptr + (size_t)64 * K + kt, As + 64 * LDK + tid * 8);
        ASYNC_COPY16(Bptr + kt,                  Bs + tid * 8);
        ASYNC_COPY16(Bptr + (size_t)64 * K + kt, Bs + 64 * LDK + tid * 8);
        __syncthreads();
        bf16x8 af[4], bfr[4];
        #pragma unroll
        for (int i = 0; i < 4; i++) af[i]  = *(const bf16x8*)&As[(wm + i * 16 + mrow) * LDK + k0];
        #pragma unroll
        for (int j = 0; j < 4; j++) bfr[j] = *(const bf16x8*)&Bs[(wn + j * 16 + mrow) * LDK + k0];
        #pragma unroll
        for (int i = 0; i < 4; i++)
            #pragma unroll
            for (int j = 0; j < 4; j++)
                acc[i][j] = __builtin_amdgcn_mfma_f32_16x16x32_bf16(af[i], bfr[j], acc[i][j], 0, 0, 0);
    }

    const int rq = (lane >> 4) << 2;
    #pragma unroll
    for (int i = 0; i < 4; i++) {
        #pragma unroll
        for (int rr = 0; rr < 4; rr++) {
            int row = tileM + wm + i * 16 + rq + rr;
            size_t base = (size_t)row * Nc + tileN + wn + mrow;
            #pragma unroll
            for (int j = 0; j < 4; j++) {
                float val = acc[i][j][rr];
                if (OUT_BF16) Cb[base + j * 16] = (__bf16)val;
                else          Cf[base + j * 16] = val;
            }
        }
    }
}

// ------------------------------------------------- FFT conv + hadamard/scale epilogue
// Input/output in pair layout: (B, 512 pair-rows, N) of uint (= bf16x2 = (dh, dh+1)).
// Forward DIF (natural in -> bitrev out), spectral pairing in bitrev addressing,
// inverse DIT (bitrev in -> natural out). Radix-2^2 quads, XOR-swizzled LDS.
__global__ __launch_bounds__(256) void fftconv(const u32* __restrict__ vt,
                                               const float* __restrict__ g_raw,
                                               const float* __restrict__ s_full,
                                               u32* __restrict__ yt) {
    __shared__ float2 Z[PN];   // 64 KB
    const int tid = threadIdx.x;
    const int row = blockIdx.x;          // b*512 + h*32 + pr
    const int bh = row >> 5;             // b*16 + h
    const u32* vp = vt + (size_t)row * PN;

    // coalesced load, natural order
    #pragma unroll
    for (int it = 0; it < 4; it++) {
        int n0 = (tid + it * 256) * 8;
        uint4 u0 = *(const uint4*)(vp + n0);
        uint4 u1 = *(const uint4*)(vp + n0 + 4);
        u32 uu[8] = {u0.x, u0.y, u0.z, u0.w, u1.x, u1.y, u1.z, u1.w};
        #pragma unroll
        for (int m = 0; m < 8; m++) {
            bf16x2 p = *(bf16x2*)&uu[m];
            Z[PHYS(n0 + m)] = f2((float)p.x, (float)p.y);
        }
    }
    __syncthreads();

    // forward DIF: 6 radix-4 quads (stages 12..1) + radix-2 stage 0
    #pragma unroll
    for (int si = 0; si < 6; si++) {
        const int s = 11 - 2 * si;
        const int h = 1 << s;
        const float ang = -6.283185307179586f / (float)(4 * h);
        for (int q = tid; q < PN / 4; q += 256) {
            int j = q & (h - 1);
            int i = ((q >> s) << (s + 2)) + j;
            float sn, cs;
            __sincosf(ang * (float)j, &sn, &cs);
            float2 w2 = f2(cs, sn);
            float2 w1 = f2(cs * cs - sn * sn, 2.f * cs * sn);
            float2 a = Z[PHYS(i)],         b = Z[PHYS(i + h)];
            float2 c = Z[PHYS(i + 2 * h)], d = Z[PHYS(i + 3 * h)];
            float2 A0 = cadd(a, c);
            float2 C0 = cmul(csub(a, c), w2);
            float2 B0 = cadd(b, d);
            float2 t  = cmul(csub(b, d), w2);
            float2 D0 = f2(t.y, -t.x);               // * (-i)
            Z[PHYS(i)]         = cadd(A0, B0);
            Z[PHYS(i + h)]     = cmul(csub(A0, B0), w1);
            Z[PHYS(i + 2 * h)] = cadd(C0, D0);
            Z[PHYS(i + 3 * h)] = cmul(csub(C0, D0), w1);
        }
        __syncthreads();
    }
    for (int q = tid; q < PN / 2; q += 256) {        // radix-2 stage 0 (no twiddle)
        int i = 2 * q;
        float2 u = Z[PHYS(i)], t = Z[PHYS(i + 1)];
        Z[PHYS(i)]     = cadd(u, t);
        Z[PHYS(i + 1)] = csub(u, t);
    }
    __syncthreads();

    // spectral stage in bitrev addressing: p even <-> k<4096; p==1 <-> k=4096
    const float* gr = g_raw + (size_t)bh * (2 * PN);
    const float* gi = gr + PN;
    for (int m = tid; m < PN / 2 + 1; m += 256) {
        int p  = (m < PN / 2) ? 2 * m : 1;
        int k  = __brev((unsigned)p) >> 19;
        int Nk = (PN - k) & (PN - 1);
        int qd = __brev((unsigned)Nk) >> 19;
        float2 Za = Z[PHYS(p)], Zb = Z[PHYS(qd)];
        float v1r = 0.5f * (Za.x + Zb.x), v1i = 0.5f * (Za.y - Zb.y);
        float v2r = 0.5f * (Za.y + Zb.y), v2i = 0.5f * (Zb.x - Za.x);
        float grk = gr[k],  gik = gi[k];
        float grn = gr[Nk], gin = gi[Nk];
        float y1r  = v1r * grk - v1i * gik, y1i  = v1r * gik + v1i * grk;
        float y2r  = v2r * grk - v2i * gik, y2i  = v2r * gik + v2i * grk;
        float y1nr = v1r * grn + v1i * gin, y1ni = v1r * gin - v1i * grn;
        float y2nr = v2r * grn + v2i * gin, y2ni = v2r * gin - v2i * grn;
        float ys1r = 0.5f * (y1r + y1nr), ys1i = 0.5f * (y1i - y1ni);
        float ys2r = 0.5f * (y2r + y2nr), ys2i = 0.5f * (y2i - y2ni);
        Z[PHYS(p)] = f2(ys1r - ys2i, ys1i + ys2r);
        if (qd != p) Z[PHYS(qd)] = f2(ys1r + ys2i, ys2r - ys1i);
    }
    __syncthreads();

    // inverse DIT: 6 radix-4 quads (stages 0..11) + radix-2 stage 12
    #pragma unroll
    for (int si = 0; si < 6; si++) {
        const int s = 2 * si;
        const int h = 1 << s;
        const float ang = 6.283185307179586f / (float)(4 * h);
        for (int q = tid; q < PN / 4; q += 256) {
            int j = q & (h - 1);
            int i = ((q >> s) << (s + 2)) + j;
            float sn, cs;
            __sincosf(ang * (float)j, &sn, &cs);
            float2 w2 = f2(cs, sn);
            float2 w1 = f2(cs * cs - sn * sn, 2.f * cs * sn);
            float2 a = Z[PHYS(i)],         b = Z[PHYS(i + h)];
            float2 c = Z[PHYS(i + 2 * h)], d = Z[PHYS(i + 3 * h)];
            float2 tb = cmul(b, w1);
            float2 p0 = cadd(a, tb), p1 = csub(a, tb);
            float2 td = cmul(d, w1);
            float2 q0 = cadd(c, td), q1 = csub(c, td);
            float2 wq0 = cmul(q0, w2);
            float2 e   = cmul(q1, w2);
            float2 ei  = f2(-e.y, e.x);              // * (+i)
            Z[PHYS(i)]         = cadd(p0, wq0);
            Z[PHYS(i + 2 * h)] = csub(p0, wq0);
            Z[PHYS(i + h)]     = cadd(p1, ei);
            Z[PHYS(i + 3 * h)] = csub(p1, ei);
        }
        __syncthreads();
    }
    {
        const float ang = 6.283185307179586f / (float)PN;
        for (int q = tid; q < PN / 2; q += 256) {    // radix-2 stage 12
            float sn, cs;
            __sincosf(ang * (float)q, &sn, &cs);
            float2 u = Z[PHYS(q)];
            float2 t = cmul(Z[PHYS(q + PN / 2)], f2(cs, sn));
            Z[PHYS(q)]          = cadd(u, t);
            Z[PHYS(q + PN / 2)] = csub(u, t);
        }
    }
    __syncthreads();

    // epilogue: v_tilde + second-butterfly(s * first-butterfly(v_tilde)), coalesced out
    const float* sp = s_full + (size_t)bh * PN;
    u32* yp = yt + (size_t)row * PN;
    const float inv = 1.0f / (float)PN;
    const float I2 = 0.70710678118654752440f;
    #pragma unroll
    for (int it = 0; it < 4; it++) {
        int nb = tid + it * 256;       // 0..1023
        int n0 = nb * 8;
        int np0 = nb * 4;
        u32 ou[8];
        #pragma unroll
        for (int pp = 0; pp < 4; pp++) {
            float2 z0 = Z[PHYS(n0 + 2 * pp)];
            float2 z1 = Z[PHYS(n0 + 2 * pp + 1)];
            float s0  = sp[np0 + pp];
            float s1v = sp[np0 + pp + PN / 2];
            float ax = z0.x * inv, ay = z0.y * inv;
            float bx = z1.x * inv, by = z1.y * inv;
            float wlx = (ax + bx) * I2 * s0, whx = (ax - bx) * I2 * s1v;
            float evx = (wlx + whx) * I2,   odx = (wlx - whx) * I2;
            float wly = (ay + by) * I2 * s0, why = (ay - by) * I2 * s1v;
            float evy = (wly + why) * I2,   ody = (wly - why) * I2;
            bf16x2 o0, o1;
            o0.x = (__bf16)(ax + evx); o0.y = (__bf16)(ay + evy);
            o1.x = (__bf16)(bx + odx); o1.y = (__bf16)(by + ody);
            ou[2 * pp]     = *(u32*)&o0;
            ou[2 * pp + 1] = *(u32*)&o1;
        }
        uint4 w0 = make_uint4(ou[0], ou[1], ou[2], ou[3]);
        uint4 w1 = make_uint4(ou[4], ou[5], ou[6], ou[7]);
        *(uint4*)(yp + n0)     = w0;
        *(uint4*)(yp + n0 + 4) = w1;
    }
}

// ================================================================ launcher
extern "C" void kernel_launch(void* const* d_in, const int* in_sizes, int n_in,
                              void* d_out, int out_size, void* d_ws, size_t ws_size,
                              hipStream_t stream) {
    const float* x    = (const float*)d_in[0];
    const float* w_q  = (const float*)d_in[1];
    const float* w_v  = (const float*)d_in[2];
    const float* w_o  = (const float*)d_in[3];
    const float* ln_g = (const float*)d_in[4];
    const float* ln_b = (const float*)d_in[5];
    const float* gw1  = (const float*)d_in[6];
    const float* gw2  = (const float*)d_in[7];
    const float* ww1  = (const float*)d_in[8];
    const float* ww2  = (const float*)d_in[9];
    float* out = (float*)d_out;

    const size_t XE = (size_t)PB * PN * PD;        // 33554432
    __bf16* xb   = (__bf16*)d_ws;                  // x bf16 -> vt (pair) -> y (b,n,d)
    __bf16* vb   = xb + XE;                        // gemm1 out -> fft out (pair)
    __bf16* wvt  = vb + XE;
    __bf16* wot  = wvt + (size_t)PD * PD;
    float*  xsum = (float*)(wot + (size_t)PD * PD);
    float*  bar  = xsum + PB * PD;
    float*  tg   = bar + PB * PD;
    float*  tw   = tg + 64 * PGH;
    float*  graw = tw + 64 * PGH;
    float*  sful = graw + (size_t)64 * 2 * PN;

    hipMemsetAsync(xsum, 0, PB * PD * sizeof(float), stream);

    convert_x<<<XE / (256 * 8), 256, 0, stream>>>(x, xb);
    transpose_w<<<dim3(PD * PD / 256, 2), 256, 0, stream>>>(w_v, w_o, wvt, wot);
    reduce_x<<<dim3(PN / 512, PD / 256, PB), 256, 0, stream>>>(x, xsum);
    barq_ln<<<dim3(PD / 256, PB), 256, 0, stream>>>(xsum, w_q, ln_g, ln_b, bar);
    small1<<<PB * PH, 256, 0, stream>>>(bar, gw1, ww1, tg, tw);
    small2<<<dim3(96, 8), 256, 0, stream>>>(tg, tw, gw2, ww2, graw, sful);
    // v = x @ w_v  (bf16, (b,n,d))
    gemm_bt<1><<<dim3(PD / 128, PB * PN / 128), 256, 0, stream>>>(xb, wvt, vb, nullptr);
    // (b, n, 512 pairs) -> (b, 512, n)
    transpose32<<<dim3(512 / 64, PN / 64, PB), 256, 0, stream>>>((const u32*)vb, (u32*)xb, PN, 512);
    // FFT conv: xb (pair layout) -> vb (pair layout)
    fftconv<<<PB * 512, 256, 0, stream>>>((const u32*)xb, graw, sful, (u32*)vb);
    // (b, 512, n) -> (b, n, 512 pairs)
    transpose32<<<dim3(PN / 64, 512 / 64, PB), 256, 0, stream>>>((const u32*)vb, (u32*)xb, 512, PN);
    // out = y @ w_o  (f32)
    gemm_bt<0><<<dim3(PD / 128, PB * PN / 128), 256, 0, stream>>>(xb, wot, nullptr, out);
}

// Round 3
// 780.639 us; speedup vs baseline: 1.3098x; 1.0869x over previous
//
#include <hip/hip_runtime.h>
#include <hip/hip_bf16.h>
#include <math.h>

#define PB 4
#define PN 8192
#define PD 1024
#define PH 16
#define PDH 64
#define PGH 256

typedef __bf16 bf16x8 __attribute__((ext_vector_type(8)));
typedef __bf16 bf16x2 __attribute__((ext_vector_type(2)));
typedef float f32x4 __attribute__((ext_vector_type(4)));
typedef unsigned int u32;
typedef unsigned short u16;

typedef __attribute__((address_space(3))) void lds_void_t;
typedef const __attribute__((address_space(1))) void gbl_void_t;
#define ASYNC_COPY16(gp, lp) \
    __builtin_amdgcn_global_load_lds((gbl_void_t*)(gp), (lds_void_t*)(lp), 16, 0, 0)

__device__ inline float gelu_exact(float x) {
    return 0.5f * x * (1.0f + erff(x * 0.70710678118654752440f));
}

__device__ inline float2 f2(float x, float y) { return make_float2(x, y); }
__device__ inline float2 cadd(float2 a, float2 b) { return f2(a.x + b.x, a.y + b.y); }
__device__ inline float2 csub(float2 a, float2 b) { return f2(a.x - b.x, a.y - b.y); }
__device__ inline float2 cmul(float2 a, float2 b) {
    return f2(a.x * b.x - a.y * b.y, a.x * b.y + a.y * b.x);
}

// XOR swizzle: uniform ~4-way (b64 floor) for every access pattern in the FFT
#define PHYS(i) ((i) ^ (((i) >> 4) & 15))

// pack two floats to bf16x2-in-u32 (low = first)
__device__ inline u32 packbf(float a, float b) {
    __bf16 ba = (__bf16)a, bb = (__bf16)b;
    return (u32)(*(u16*)&ba) | ((u32)(*(u16*)&bb) << 16);
}

// ---------------------------------------------------------------- convert x -> bf16
__global__ void convert_x(const float* __restrict__ x, __bf16* __restrict__ xb) {
    int i = (blockIdx.x * 256 + threadIdx.x) * 8;
    float4 f0 = *(const float4*)(x + i);
    float4 f1 = *(const float4*)(x + i + 4);
    bf16x8 o;
    o[0] = (__bf16)f0.x; o[1] = (__bf16)f0.y; o[2] = (__bf16)f0.z; o[3] = (__bf16)f0.w;
    o[4] = (__bf16)f1.x; o[5] = (__bf16)f1.y; o[6] = (__bf16)f1.z; o[7] = (__bf16)f1.w;
    *(bf16x8*)(xb + i) = o;
}

// ------------------------------------------- transpose+convert w_v, w_o -> bf16 N x K
__global__ void transpose_w(const float* __restrict__ wv, const float* __restrict__ wo,
                            __bf16* __restrict__ wvt, __bf16* __restrict__ wot) {
    int idx = blockIdx.x * 256 + threadIdx.x;
    const float* src = blockIdx.y ? wo : wv;
    __bf16* dst = blockIdx.y ? wot : wvt;
    int r = idx >> 10, c = idx & 1023;
    dst[c * PD + r] = (__bf16)src[idx];
}

// ---------------------------------------------------------------- xsum[b,d] = sum_n x
__global__ void reduce_x(const float* __restrict__ x, float* __restrict__ xsum) {
    int b = blockIdx.z;
    int d = blockIdx.y * 256 + threadIdx.x;
    int n0 = blockIdx.x * 512;
    const float* p = x + ((size_t)b * PN + n0) * PD + d;
    float s = 0.0f;
    for (int i = 0; i < 512; i++) s += p[(size_t)i * PD];
    atomicAdd(&xsum[b * PD + d], s);
}

// --------------------------------- bar_q = (xsum/N) @ w_q, then LayerNorm over DH=64
__global__ void barq_ln(const float* __restrict__ xsum, const float* __restrict__ w_q,
                        const float* __restrict__ ln_g, const float* __restrict__ ln_b,
                        float* __restrict__ bar_ln) {
    int b = blockIdx.y;
    int c = blockIdx.x * 256 + threadIdx.x;
    const float* xs = xsum + b * PD;
    float acc = 0.0f;
    for (int k = 0; k < PD; k++) acc += xs[k] * w_q[k * PD + c];
    float bar = acc * (1.0f / (float)PN);
    float mu = bar;
    for (int o = 32; o > 0; o >>= 1) mu += __shfl_xor(mu, o, 64);
    mu *= (1.0f / 64.0f);
    float d0 = bar - mu;
    float vv = d0 * d0;
    for (int o = 32; o > 0; o >>= 1) vv += __shfl_xor(vv, o, 64);
    vv *= (1.0f / 64.0f);
    int dh = c & 63;
    bar_ln[b * PD + c] = d0 * rsqrtf(vv + 1e-5f) * ln_g[dh] + ln_b[dh];
}

// ---------------------------- t_gate = gelu(bar@gate_w1); t_wrm = gelu(bar@wrm_w1)
__global__ void small1(const float* __restrict__ bar_ln, const float* __restrict__ gw1,
                       const float* __restrict__ ww1, float* __restrict__ tg,
                       float* __restrict__ tw) {
    int bh = blockIdx.x;
    int j = threadIdx.x;
    __shared__ float bl[PDH];
    if (j < PDH) bl[j] = bar_ln[bh * PDH + j];
    __syncthreads();
    float a1 = 0.0f, a2 = 0.0f;
    for (int k = 0; k < PDH; k++) {
        float bv = bl[k];
        a1 += bv * gw1[k * PGH + j];
        a2 += bv * ww1[k * PGH + j];
    }
    tg[bh * PGH + j] = gelu_exact(a1);
    tw[bh * PGH + j] = gelu_exact(a2);
}

// ---------------------- g_raw = t_gate@gate_w2 (64x16384); s = t_wrm@wrm_w2 (64x8192)
__global__ void small2(const float* __restrict__ tg, const float* __restrict__ tw,
                       const float* __restrict__ gw2, const float* __restrict__ ww2,
                       float* __restrict__ g_raw, float* __restrict__ s_full) {
    int chunk = blockIdx.x;
    int bh0 = blockIdx.y * 8;
    bool isg = chunk < 64;
    const float* t = isg ? tg : tw;
    const float* w2 = isg ? gw2 : ww2;
    int stride = isg ? (2 * PN) : PN;
    int col = (isg ? chunk : chunk - 64) * 256 + threadIdx.x;
    __shared__ float tl[8][PGH];
    #pragma unroll
    for (int i = 0; i < 8; i++) tl[i][threadIdx.x] = t[(bh0 + i) * PGH + threadIdx.x];
    __syncthreads();
    float acc[8] = {0, 0, 0, 0, 0, 0, 0, 0};
    for (int k = 0; k < PGH; k++) {
        float w = w2[(size_t)k * stride + col];
        #pragma unroll
        for (int i = 0; i < 8; i++) acc[i] += tl[i][k] * w;
    }
    #pragma unroll
    for (int i = 0; i < 8; i++) {
        if (isg) g_raw[(size_t)(bh0 + i) * (2 * PN) + col] = acc[i];
        else     s_full[(size_t)(bh0 + i) * PN + col] = acc[i];
    }
}

// --------------------------------------------- GEMM1: C = A * Bt^T, pair-layout output
// Output written directly as vt (b, 512 pair-rows, 8192 n) of u32 (bf16 lo=even col).
__global__ __launch_bounds__(256) void gemm_pair(const __bf16* __restrict__ A,
                                                 const __bf16* __restrict__ Bt,
                                                 u32* __restrict__ vt) {
    constexpr int K = PD, LDK = 32;
    __shared__ __attribute__((aligned(16))) __bf16 As[128 * LDK];
    __shared__ __attribute__((aligned(16))) __bf16 Bs[128 * LDK];
    const int tid = threadIdx.x;
    const int lane = tid & 63;
    const int wave = tid >> 6;
    const int wm = (wave >> 1) << 6;
    const int wn = (wave & 1) << 6;
    const int tileM = blockIdx.y << 7;
    const int tileN = blockIdx.x << 7;
    const int r = tid >> 2;
    const int cg = tid & 3;
    const int mrow = lane & 15;
    const int k0 = (lane >> 4) << 3;

    f32x4 acc[4][4] = {};
    const __bf16* Aptr = A + (size_t)(tileM + r) * K + cg * 8;
    const __bf16* Bptr = Bt + (size_t)(tileN + r) * K + cg * 8;

    for (int kt = 0; kt < K; kt += 32) {
        __syncthreads();
        ASYNC_COPY16(Aptr + kt,                  As + tid * 8);
        ASYNC_COPY16(Aptr + (size_t)64 * K + kt, As + 64 * LDK + tid * 8);
        ASYNC_COPY16(Bptr + kt,                  Bs + tid * 8);
        ASYNC_COPY16(Bptr + (size_t)64 * K + kt, Bs + 64 * LDK + tid * 8);
        __syncthreads();
        bf16x8 af[4], bfr[4];
        #pragma unroll
        for (int i = 0; i < 4; i++) af[i]  = *(const bf16x8*)&As[(wm + i * 16 + mrow) * LDK + k0];
        #pragma unroll
        for (int j = 0; j < 4; j++) bfr[j] = *(const bf16x8*)&Bs[(wn + j * 16 + mrow) * LDK + k0];
        #pragma unroll
        for (int i = 0; i < 4; i++)
            #pragma unroll
            for (int j = 0; j < 4; j++)
                acc[i][j] = __builtin_amdgcn_mfma_f32_16x16x32_bf16(af[i], bfr[j], acc[i][j], 0, 0, 0);
    }

    // epilogue: pair columns live in adjacent lanes (same rows) -> shfl_xor(1) pack,
    // even lanes store uint4 (4 consecutive n) into pair-layout vt.
    const int rq = (lane >> 4) << 2;
    const bool evl = (lane & 1) == 0;
    #pragma unroll
    for (int i = 0; i < 4; i++) {
        int grow = tileM + wm + i * 16 + rq;       // base of 4 consecutive rows
        int b = grow >> 13;
        int nb = grow & 8191;
        #pragma unroll
        for (int j = 0; j < 4; j++) {
            u32 w[4];
            #pragma unroll
            for (int rr = 0; rr < 4; rr++) {
                float a = acc[i][j][rr];
                float o = __shfl_xor(a, 1, 64);
                w[rr] = packbf(a, o);              // even lane: (own=2P, odd=2P+1)
            }
            if (evl) {
                int col = tileN + wn + j * 16 + mrow;
                size_t idx = ((size_t)b * 512 + (col >> 1)) * PN + nb;
                *(uint4*)(vt + idx) = make_uint4(w[0], w[1], w[2], w[3]);
            }
        }
    }
}

// ----------------------------- GEMM2: C = Y * Bt^T with Y given in pair layout (=Y^T)
// A-tiles staged from yt (b,512,8192) u32 rows (coalesced), scattered to As[m][k].
__global__ __launch_bounds__(256) void gemm_ta(const u32* __restrict__ yt,
                                               const __bf16* __restrict__ Bt,
                                               float* __restrict__ Cf) {
    constexpr int K = PD, Nc = PD, LDKA = 40, LDKB = 32;
    __shared__ __attribute__((aligned(16))) __bf16 As[128 * LDKA];
    __shared__ __attribute__((aligned(16))) __bf16 Bs[128 * LDKB];
    u32* As32 = (u32*)As;                      // As32[m*20 + p] = cols k=2p,2p+1 of row m
    const int tid = threadIdx.x;
    const int lane = tid & 63;
    const int wave = tid >> 6;
    const int wm = (wave >> 1) << 6;
    const int wn = (wave & 1) << 6;
    const int tileM = blockIdx.y << 7;
    const int tileN = blockIdx.x << 7;
    const int r = tid >> 2;
    const int cg = tid & 3;
    const int mrow = lane & 15;
    const int k0 = (lane >> 4) << 3;
    const int prow = tid & 7;                  // pair-row within tile (and +8)
    const int seg = tid >> 3;                  // n-segment (4 u32)

    const int b = tileM >> 13;
    const int n0 = tileM & 8191;
    const u32* abase = yt + ((size_t)b * 512 + prow) * PN + n0 + seg * 4;
    const __bf16* Bptr = Bt + (size_t)(tileN + r) * K + cg * 8;

    f32x4 acc[4][4] = {};
    uint4 pa0 = *(const uint4*)(abase);
    uint4 pa1 = *(const uint4*)(abase + (size_t)8 * PN);

    for (int kt = 0; kt < K; kt += 32) {
        __syncthreads();
        {
            int m0 = seg * 4;
            As32[(m0 + 0) * 20 + prow] = pa0.x;
            As32[(m0 + 1) * 20 + prow] = pa0.y;
            As32[(m0 + 2) * 20 + prow] = pa0.z;
            As32[(m0 + 3) * 20 + prow] = pa0.w;
            As32[(m0 + 0) * 20 + prow + 8] = pa1.x;
            As32[(m0 + 1) * 20 + prow + 8] = pa1.y;
            As32[(m0 + 2) * 20 + prow + 8] = pa1.z;
            As32[(m0 + 3) * 20 + prow + 8] = pa1.w;
        }
        ASYNC_COPY16(Bptr + kt,                  Bs + tid * 8);
        ASYNC_COPY16(Bptr + (size_t)64 * K + kt, Bs + 64 * LDKB + tid * 8);
        if (kt + 32 < K) {
            const u32* nxt = abase + (size_t)((kt >> 1) + 16) * PN;
            pa0 = *(const uint4*)(nxt);
            pa1 = *(const uint4*)(nxt + (size_t)8 * PN);
        }
        __syncthreads();
        bf16x8 af[4], bfr[4];
        #pragma unroll
        for (int i = 0; i < 4; i++) af[i]  = *(const bf16x8*)&As[(wm + i * 16 + mrow) * LDKA + k0];
        #pragma unroll
        for (int j = 0; j < 4; j++) bfr[j] = *(const bf16x8*)&Bs[(wn + j * 16 + mrow) * LDKB + k0];
        #pragma unroll
        for (int i = 0; i < 4; i++)
            #pragma unroll
            for (int j = 0; j < 4; j++)
                acc[i][j] = __builtin_amdgcn_mfma_f32_16x16x32_bf16(af[i], bfr[j], acc[i][j], 0, 0, 0);
    }

    const int rq = (lane >> 4) << 2;
    #pragma unroll
    for (int i = 0; i < 4; i++) {
        #pragma unroll
        for (int rr = 0; rr < 4; rr++) {
            int row = tileM + wm + i * 16 + rq + rr;
            size_t base = (size_t)row * Nc + tileN + wn + mrow;
            #pragma unroll
            for (int j = 0; j < 4; j++) Cf[base + j * 16] = acc[i][j][rr];
        }
    }
}

// ------------------------------------------------- FFT conv + hadamard/scale epilogue
// 512 threads/block; pair layout in/out. Fwd DIF (nat->bitrev), spectral in bitrev,
// inv DIT (bitrev->nat). Radix-2^2, XOR-swizzled LDS, hoisted/incremental twiddles.
__global__ __launch_bounds__(512) void fftconv(const u32* __restrict__ vt,
                                               const float* __restrict__ g_raw,
                                               const float* __restrict__ s_full,
                                               u32* __restrict__ yt) {
    __shared__ float2 Z[PN];   // 64 KB
    const int tid = threadIdx.x;           // 0..511
    const int row = blockIdx.x;            // b*512 + pair
    const int bh = row >> 5;
    const u32* vp = vt + (size_t)row * PN;

    #pragma unroll
    for (int it = 0; it < 2; it++) {
        int n0 = (tid + it * 512) * 8;
        uint4 u0 = *(const uint4*)(vp + n0);
        uint4 u1 = *(const uint4*)(vp + n0 + 4);
        u32 uu[8] = {u0.x, u0.y, u0.z, u0.w, u1.x, u1.y, u1.z, u1.w};
        #pragma unroll
        for (int m = 0; m < 8; m++) {
            bf16x2 p = *(bf16x2*)&uu[m];
            Z[PHYS(n0 + m)] = f2((float)p.x, (float)p.y);
        }
    }
    __syncthreads();

    // forward DIF: radix-4 stages s=11,9,7,5,3,1 then radix-2 s=0
    #pragma unroll
    for (int si = 0; si < 6; si++) {
        const int s = 11 - 2 * si;
        const int h = 1 << s;
        const float ang = -6.283185307179586f / (float)(4 * h);
        float sn, cs;
        __sincosf(ang * (float)(tid & (h - 1)), &sn, &cs);
        float2 w2 = f2(cs, sn);
        #pragma unroll
        for (int it = 0; it < 4; it++) {
            int q = tid + it * 512;
            int i = ((q >> s) << (s + 2)) + (q & (h - 1));
            float2 w1 = cmul(w2, w2);
            float2 a = Z[PHYS(i)],         bb = Z[PHYS(i + h)];
            float2 c = Z[PHYS(i + 2 * h)], d  = Z[PHYS(i + 3 * h)];
            float2 A0 = cadd(a, c);
            float2 C0 = cmul(csub(a, c), w2);
            float2 B0 = cadd(bb, d);
            float2 t  = cmul(csub(bb, d), w2);
            float2 D0 = f2(t.y, -t.x);               // * (-i)
            Z[PHYS(i)]         = cadd(A0, B0);
            Z[PHYS(i + h)]     = cmul(csub(A0, B0), w1);
            Z[PHYS(i + 2 * h)] = cadd(C0, D0);
            Z[PHYS(i + 3 * h)] = cmul(csub(C0, D0), w1);
            if (h == 2048) w2 = cmul(w2, f2(0.92387953251f, -0.38268343236f)); // cis(-pi/8)
        }
        __syncthreads();
    }
    #pragma unroll
    for (int it = 0; it < 8; it++) {               // radix-2 s=0, twiddle-free
        int i = 2 * (tid + it * 512);
        float2 u = Z[PHYS(i)], t = Z[PHYS(i + 1)];
        Z[PHYS(i)]     = cadd(u, t);
        Z[PHYS(i + 1)] = csub(u, t);
    }
    __syncthreads();

    // spectral stage in bitrev addressing
    const float* gr = g_raw + (size_t)bh * (2 * PN);
    const float* gi = gr + PN;
    for (int m = tid; m < PN / 2 + 1; m += 512) {
        int p  = (m < PN / 2) ? 2 * m : 1;
        int k  = __brev((unsigned)p) >> 19;
        int Nk = (PN - k) & (PN - 1);
        int qd = __brev((unsigned)Nk) >> 19;
        float2 Za = Z[PHYS(p)], Zb = Z[PHYS(qd)];
        float v1r = 0.5f * (Za.x + Zb.x), v1i = 0.5f * (Za.y - Zb.y);
        float v2r = 0.5f * (Za.y + Zb.y), v2i = 0.5f * (Zb.x - Za.x);
        float grk = gr[k],  gik = gi[k];
        float grn = gr[Nk], gin = gi[Nk];
        float y1r  = v1r * grk - v1i * gik, y1i  = v1r * gik + v1i * grk;
        float y2r  = v2r * grk - v2i * gik, y2i  = v2r * gik + v2i * grk;
        float y1nr = v1r * grn + v1i * gin, y1ni = v1r * gin - v1i * grn;
        float y2nr = v2r * grn + v2i * gin, y2ni = v2r * gin - v2i * grn;
        float ys1r = 0.5f * (y1r + y1nr), ys1i = 0.5f * (y1i - y1ni);
        float ys2r = 0.5f * (y2r + y2nr), ys2i = 0.5f * (y2i - y2ni);
        Z[PHYS(p)] = f2(ys1r - ys2i, ys1i + ys2r);
        if (qd != p) Z[PHYS(qd)] = f2(ys1r + ys2i, ys2r - ys1i);
    }
    __syncthreads();

    // inverse DIT: radix-4 stages s=0,2,4,6,8,10 then radix-2 s=12
    #pragma unroll
    for (int si = 0; si < 6; si++) {
        const int s = 2 * si;
        const int h = 1 << s;
        const float ang = 6.283185307179586f / (float)(4 * h);
        float sn, cs;
        __sincosf(ang * (float)(tid & (h - 1)), &sn, &cs);
        float2 w2a = f2(cs, sn);
        float2 w2b = (h == 1024) ? cmul(w2a, f2(0.70710678119f, 0.70710678119f)) : w2a;
        #pragma unroll
        for (int it = 0; it < 4; it++) {
            int q = tid + it * 512;
            int i = ((q >> s) << (s + 2)) + (q & (h - 1));
            float2 w2 = (it & 1) ? w2b : w2a;
            float2 w1 = cmul(w2, w2);
            float2 a = Z[PHYS(i)],         bb = Z[PHYS(i + h)];
            float2 c = Z[PHYS(i + 2 * h)], d  = Z[PHYS(i + 3 * h)];
            float2 tb = cmul(bb, w1);
            float2 p0 = cadd(a, tb), p1 = csub(a, tb);
            float2 td = cmul(d, w1);
            float2 q0 = cadd(c, td), q1 = csub(c, td);
            float2 wq0 = cmul(q0, w2);
            float2 e   = cmul(q1, w2);
            float2 ei  = f2(-e.y, e.x);              // * (+i)
            Z[PHYS(i)]         = cadd(p0, wq0);
            Z[PHYS(i + 2 * h)] = csub(p0, wq0);
            Z[PHYS(i + h)]     = cadd(p1, ei);
            Z[PHYS(i + 3 * h)] = csub(p1, ei);
        }
        __syncthreads();
    }
    {
        const float ang = 6.283185307179586f / (float)PN;
        float sn, cs;
        __sincosf(ang * (float)tid, &sn, &cs);
        float2 w = f2(cs, sn);
        #pragma unroll
        for (int it = 0; it < 8; it++) {           // radix-2 s=12, chained twiddle
            int q = tid + it * 512;
            float2 u = Z[PHYS(q)];
            float2 t = cmul(Z[PHYS(q + PN / 2)], w);
            Z[PHYS(q)]          = cadd(u, t);
            Z[PHYS(q + PN / 2)] = csub(u, t);
            w = cmul(w, f2(0.92387953251f, 0.38268343236f)); // cis(+pi/8)
        }
    }
    __syncthreads();

    // epilogue: v_tilde + second-butterfly(s * first-butterfly(v_tilde))
    const float* sp = s_full + (size_t)bh * PN;
    u32* yp = yt + (size_t)row * PN;
    const float inv = 1.0f / (float)PN;
    const float I2 = 0.70710678118654752440f;
    #pragma unroll
    for (int it = 0; it < 2; it++) {
        int nb = tid + it * 512;       // 0..1023
        int n0 = nb * 8;
        int np0 = nb * 4;
        u32 ou[8];
        #pragma unroll
        for (int pp = 0; pp < 4; pp++) {
            float2 z0 = Z[PHYS(n0 + 2 * pp)];
            float2 z1 = Z[PHYS(n0 + 2 * pp + 1)];
            float s0  = sp[np0 + pp];
            float s1v = sp[np0 + pp + PN / 2];
            float ax = z0.x * inv, ay = z0.y * inv;
            float bx = z1.x * inv, by = z1.y * inv;
            float wlx = (ax + bx) * I2 * s0, whx = (ax - bx) * I2 * s1v;
            float evx = (wlx + whx) * I2,   odx = (wlx - whx) * I2;
            float wly = (ay + by) * I2 * s0, why = (ay - by) * I2 * s1v;
            float evy = (wly + why) * I2,   ody = (wly - why) * I2;
            ou[2 * pp]     = packbf(ax + evx, ay + evy);
            ou[2 * pp + 1] = packbf(bx + odx, by + ody);
        }
        *(uint4*)(yp + n0)     = make_uint4(ou[0], ou[1], ou[2], ou[3]);
        *(uint4*)(yp + n0 + 4) = make_uint4(ou[4], ou[5], ou[6], ou[7]);
    }
}

// ================================================================ launcher
extern "C" void kernel_launch(void* const* d_in, const int* in_sizes, int n_in,
                              void* d_out, int out_size, void* d_ws, size_t ws_size,
                              hipStream_t stream) {
    const float* x    = (const float*)d_in[0];
    const float* w_q  = (const float*)d_in[1];
    const float* w_v  = (const float*)d_in[2];
    const float* w_o  = (const float*)d_in[3];
    const float* ln_g = (const float*)d_in[4];
    const float* ln_b = (const float*)d_in[5];
    const float* gw1  = (const float*)d_in[6];
    const float* gw2  = (const float*)d_in[7];
    const float* ww1  = (const float*)d_in[8];
    const float* ww2  = (const float*)d_in[9];
    float* out = (float*)d_out;

    const size_t XE = (size_t)PB * PN * PD;        // 33554432
    __bf16* xb   = (__bf16*)d_ws;                  // x bf16; later reused: fft out (pair)
    __bf16* vb   = xb + XE;                        // gemm1 out (pair layout)
    __bf16* wvt  = vb + XE;
    __bf16* wot  = wvt + (size_t)PD * PD;
    float*  xsum = (float*)(wot + (size_t)PD * PD);
    float*  bar  = xsum + PB * PD;
    float*  tg   = bar + PB * PD;
    float*  tw   = tg + 64 * PGH;
    float*  graw = tw + 64 * PGH;
    float*  sful = graw + (size_t)64 * 2 * PN;

    hipMemsetAsync(xsum, 0, PB * PD * sizeof(float), stream);

    convert_x<<<XE / (256 * 8), 256, 0, stream>>>(x, xb);
    transpose_w<<<dim3(PD * PD / 256, 2), 256, 0, stream>>>(w_v, w_o, wvt, wot);
    reduce_x<<<dim3(PN / 512, PD / 256, PB), 256, 0, stream>>>(x, xsum);
    barq_ln<<<dim3(PD / 256, PB), 256, 0, stream>>>(xsum, w_q, ln_g, ln_b, bar);
    small1<<<PB * PH, 256, 0, stream>>>(bar, gw1, ww1, tg, tw);
    small2<<<dim3(96, 8), 256, 0, stream>>>(tg, tw, gw2, ww2, graw, sful);
    // v = x @ w_v, written directly in pair-transposed layout
    gemm_pair<<<dim3(PD / 128, PB * PN / 128), 256, 0, stream>>>(xb, wvt, (u32*)vb);
    // FFT conv: vb (pair) -> xb (pair)
    fftconv<<<PB * 512, 512, 0, stream>>>((const u32*)vb, graw, sful, (u32*)xb);
    // out = y @ w_o, A staged from pair layout
    gemm_ta<<<dim3(PD / 128, PB * PN / 128), 256, 0, stream>>>((const u32*)xb, wot, out);
}